// Round 1
// baseline (2828.326 us; speedup 1.0000x reference)
//
#include <hip/hip_runtime.h>

#define NN 50000
#define NE 800000
#define D  128

// ---------------------------------------------------------------------------
// Kernel 1: edge scatter. 32 threads per directed edge; lane f4 handles
// features [4*f4, 4*f4+4). ax accumulates directly into d_out.
// ---------------------------------------------------------------------------
__global__ __launch_bounds__(256) void gc_scatter(
    const int* __restrict__ edges, const float* __restrict__ wts,
    const float* __restrict__ X, float* __restrict__ ax, float* __restrict__ deg)
{
    unsigned long long g = (unsigned long long)blockIdx.x * 256ull + threadIdx.x;
    const unsigned long long total = (unsigned long long)2 * NE * 32;
    if (g >= total) return;
    unsigned int e2 = (unsigned int)(g >> 5);
    unsigned int f4 = (unsigned int)(g & 31u);
    unsigned int e  = (e2 < NE) ? e2 : e2 - NE;
    int src, dst;
    if (e2 < NE) { src = edges[2 * e];     dst = edges[2 * e + 1]; }
    else         { src = edges[2 * e + 1]; dst = edges[2 * e];     }
    float w = wts[e];
    if (f4 == 0) atomicAdd(deg + dst, w);
    const float4 xv = *reinterpret_cast<const float4*>(X + (size_t)src * D + f4 * 4);
    float* o = ax + (size_t)dst * D + f4 * 4;
    atomicAdd(o + 0, w * xv.x);
    atomicAdd(o + 1, w * xv.y);
    atomicAdd(o + 2, w * xv.z);
    atomicAdd(o + 3, w * xv.w);
}

// ---------------------------------------------------------------------------
// Kernel 2: out_rows = (ax_rows * inv_deg) @ W, in place. Each block owns 16
// rows: stages them + all of W in LDS, computes, overwrites the same 16 rows.
// block = 256 threads = (col 0..127) x (ty 0..1); 8 rows per thread.
// ---------------------------------------------------------------------------
__global__ __launch_bounds__(256) void gc_gemm_inplace(
    float* __restrict__ axout, const float* __restrict__ deg,
    const float* __restrict__ Wm)
{
    __shared__ float Ws[D * D];        // 64 KB
    __shared__ float axs[16 * D];      // 8 KB
    const int tid = threadIdx.x;
    const int col = tid & 127;
    const int ty  = tid >> 7;          // 0 or 1
    const int rbase = blockIdx.x * 16;

    // stage W: 4096 float4, 16 per thread (coalesced)
    const float4* W4  = reinterpret_cast<const float4*>(Wm);
    float4*       Ws4 = reinterpret_cast<float4*>(Ws);
    #pragma unroll
    for (int i = 0; i < 16; ++i) Ws4[tid + i * 256] = W4[tid + i * 256];

    // stage 16 ax rows: 512 float4, 2 per thread
    const float4* A4   = reinterpret_cast<const float4*>(axout + (size_t)rbase * D);
    float4*       axs4 = reinterpret_cast<float4*>(axs);
    #pragma unroll
    for (int i = 0; i < 2; ++i) axs4[tid + i * 256] = A4[tid + i * 256];
    __syncthreads();

    float acc[8];
    #pragma unroll
    for (int i = 0; i < 8; ++i) acc[i] = 0.f;

    for (int k = 0; k < D; ++k) {
        float wv = Ws[k * D + col];            // lanes stride-1 -> 2/bank, free
        #pragma unroll
        for (int i = 0; i < 8; ++i)            // uniform addr per wave -> broadcast
            acc[i] = fmaf(axs[(ty * 8 + i) * D + k], wv, acc[i]);
    }

    #pragma unroll
    for (int i = 0; i < 8; ++i) {
        int r = rbase + ty * 8 + i;
        float dg  = deg[r];
        float inv = dg > 0.f ? 1.f / dg : 0.f;
        axout[(size_t)r * D + col] = acc[i] * inv;
    }
}

extern "C" void kernel_launch(void* const* d_in, const int* in_sizes, int n_in,
                              void* d_out, int out_size, void* d_ws, size_t ws_size,
                              hipStream_t stream) {
    const float* X     = (const float*)d_in[0];   // [N,128]
    const int*   edges = (const int*)d_in[1];     // [E,2]
    const float* wts   = (const float*)d_in[2];   // [E]
    const float* Wm    = (const float*)d_in[3];   // [128,128]
    float* out = (float*)d_out;                   // [N,128]
    float* deg = (float*)d_ws;                    // [N]

    hipMemsetAsync(out, 0, (size_t)NN * D * sizeof(float), stream);
    hipMemsetAsync(deg, 0, (size_t)NN * sizeof(float), stream);

    const unsigned long long total = (unsigned long long)2 * NE * 32;
    const unsigned int blocks = (unsigned int)((total + 255) / 256);
    gc_scatter<<<blocks, 256, 0, stream>>>(edges, wts, X, out, deg);
    gc_gemm_inplace<<<NN / 16, 256, 0, stream>>>(out, deg, Wm);
}

// Round 2
// 595.547 us; speedup vs baseline: 4.7491x; 4.7491x over previous
//
#include <hip/hip_runtime.h>

#define NN 50000
#define NE 800000
#define D  128

// ---- workspace layout (bytes, 256-aligned regions) ----
// degw      float[NN]     @ 0
// counts    int[NN]       @ 200704
// row_start int[NN+1]     @ 401408
// cursor    int[NN]       @ 602112
// cols      int[2E]       @ 802816
// vals      float[2E]     @ 7202816     (end: 13,602,816)
#define OFF_DEGW   0
#define OFF_CNT    200704
#define OFF_ROW    401408
#define OFF_CUR    602112
#define OFF_COLS   802816
#define OFF_VALS   7202816

// K1: per-edge histogram (both directions) + weighted degree
__global__ __launch_bounds__(256) void gc_hist(
    const int2* __restrict__ edges, const float* __restrict__ wts,
    int* __restrict__ counts, float* __restrict__ degw)
{
    int e = blockIdx.x * 256 + threadIdx.x;
    if (e >= NE) return;
    int2 p = edges[e];
    float w = wts[e];
    atomicAdd(counts + p.x, 1);
    atomicAdd(counts + p.y, 1);
    atomicAdd(degw + p.x, w);
    atomicAdd(degw + p.y, w);
}

// K2: single-block exclusive scan of counts -> row_start, cursor
__global__ __launch_bounds__(1024) void gc_scan(
    const int* __restrict__ counts, int* __restrict__ row_start,
    int* __restrict__ cursor)
{
    const int CHUNK = (NN + 1023) / 1024;   // 49
    __shared__ int part[1024];
    int t = threadIdx.x;
    int lo = t * CHUNK, hi = min(lo + CHUNK, NN);
    int s = 0;
    for (int i = lo; i < hi; ++i) s += counts[i];
    part[t] = s;
    __syncthreads();
    // Hillis-Steele inclusive scan over 1024 partials
    for (int off = 1; off < 1024; off <<= 1) {
        int v = (t >= off) ? part[t - off] : 0;
        __syncthreads();
        part[t] += v;
        __syncthreads();
    }
    int run = part[t] - s;                  // exclusive prefix
    for (int i = lo; i < hi; ++i) {
        int c = counts[i];
        row_start[i] = run;
        cursor[i]    = run;
        run += c;
    }
    if (t == 1023) row_start[NN] = part[1023];
}

// K3: fill CSR (cols, vals) via per-node cursors
__global__ __launch_bounds__(256) void gc_fill(
    const int2* __restrict__ edges, const float* __restrict__ wts,
    int* __restrict__ cursor, int* __restrict__ cols, float* __restrict__ vals)
{
    int e = blockIdx.x * 256 + threadIdx.x;
    if (e >= NE) return;
    int2 p = edges[e];
    float w = wts[e];
    int pos = atomicAdd(cursor + p.y, 1);   // edge src->dst contributes to dst
    cols[pos] = p.x; vals[pos] = w;
    pos = atomicAdd(cursor + p.x, 1);       // and reverse direction
    cols[pos] = p.y; vals[pos] = w;
}

// K4: gather. One 64-lane wave per node; lane owns float2 of the row.
__global__ __launch_bounds__(256) void gc_gather(
    const int* __restrict__ row_start, const int* __restrict__ cols,
    const float* __restrict__ vals, const float* __restrict__ X,
    const float* __restrict__ degw, float* __restrict__ out)
{
    int wid  = (blockIdx.x * 256 + threadIdx.x) >> 6;
    int lane = threadIdx.x & 63;
    if (wid >= NN) return;
    int j   = row_start[wid];
    int end = row_start[wid + 1];
    const float2* X2 = reinterpret_cast<const float2*>(X);
    float ax = 0.f, ay = 0.f;
    for (; j < end; ++j) {
        int   c = cols[j];                  // same addr across wave -> broadcast
        float w = vals[j];
        float2 xv = X2[(size_t)c * 64 + lane];  // coalesced 512B row read
        ax = fmaf(w, xv.x, ax);
        ay = fmaf(w, xv.y, ay);
    }
    float dg  = degw[wid];
    float inv = dg > 0.f ? 1.f / dg : 0.f;
    float2 r; r.x = ax * inv; r.y = ay * inv;
    reinterpret_cast<float2*>(out)[(size_t)wid * 64 + lane] = r;
}

// K5: out_rows = ax_rows @ W, in place. Block owns 16 rows; W + rows in LDS.
__global__ __launch_bounds__(256) void gc_gemm_inplace(
    float* __restrict__ axout, const float* __restrict__ Wm)
{
    __shared__ float Ws[D * D];        // 64 KB
    __shared__ float axs[16 * D];      // 8 KB
    const int tid = threadIdx.x;
    const int col = tid & 127;
    const int ty  = tid >> 7;          // 0 or 1
    const int rbase = blockIdx.x * 16;

    const float4* W4  = reinterpret_cast<const float4*>(Wm);
    float4*       Ws4 = reinterpret_cast<float4*>(Ws);
    #pragma unroll
    for (int i = 0; i < 16; ++i) Ws4[tid + i * 256] = W4[tid + i * 256];

    const float4* A4   = reinterpret_cast<const float4*>(axout + (size_t)rbase * D);
    float4*       axs4 = reinterpret_cast<float4*>(axs);
    #pragma unroll
    for (int i = 0; i < 2; ++i) axs4[tid + i * 256] = A4[tid + i * 256];
    __syncthreads();

    float acc[8];
    #pragma unroll
    for (int i = 0; i < 8; ++i) acc[i] = 0.f;

    for (int k = 0; k < D; ++k) {
        float wv = Ws[k * D + col];
        #pragma unroll
        for (int i = 0; i < 8; ++i)
            acc[i] = fmaf(axs[(ty * 8 + i) * D + k], wv, acc[i]);
    }

    #pragma unroll
    for (int i = 0; i < 8; ++i)
        axout[(size_t)(rbase + ty * 8 + i) * D + col] = acc[i];
}

extern "C" void kernel_launch(void* const* d_in, const int* in_sizes, int n_in,
                              void* d_out, int out_size, void* d_ws, size_t ws_size,
                              hipStream_t stream) {
    const float* X     = (const float*)d_in[0];   // [N,128]
    const int2*  edges = (const int2*)d_in[1];    // [E,2]
    const float* wts   = (const float*)d_in[2];   // [E]
    const float* Wm    = (const float*)d_in[3];   // [128,128]
    float* out = (float*)d_out;                   // [N,128]

    char* ws = (char*)d_ws;
    float* degw      = (float*)(ws + OFF_DEGW);
    int*   counts    = (int*)  (ws + OFF_CNT);
    int*   row_start = (int*)  (ws + OFF_ROW);
    int*   cursor    = (int*)  (ws + OFF_CUR);
    int*   cols      = (int*)  (ws + OFF_COLS);
    float* vals      = (float*)(ws + OFF_VALS);

    hipMemsetAsync(degw,   0, NN * sizeof(float), stream);
    hipMemsetAsync(counts, 0, NN * sizeof(int),   stream);

    const int eblocks = (NE + 255) / 256;
    gc_hist<<<eblocks, 256, 0, stream>>>(edges, wts, counts, degw);
    gc_scan<<<1, 1024, 0, stream>>>(counts, row_start, cursor);
    gc_fill<<<eblocks, 256, 0, stream>>>(edges, wts, cursor, cols, vals);
    gc_gather<<<(NN * 64 + 255) / 256, 256, 0, stream>>>(row_start, cols, vals, X, degw, out);
    gc_gemm_inplace<<<NN / 16, 256, 0, stream>>>(out, Wm);
}

// Round 3
// 523.481 us; speedup vs baseline: 5.4029x; 1.1377x over previous
//
#include <hip/hip_runtime.h>

#define NN 50000
#define NE 800000
#define D  128

// ---- workspace layout (bytes) ----
#define OFF_CNT    0           // counts    int[NN]
#define OFF_ROW    200704      // row_start int[NN+1]
#define OFF_CUR    401408      // cursor    int[NN]
#define OFF_CSR    602112      // csr       int2[2E]  (col, w-bits)  12.8 MB
#define OFF_XW     13402112    // XW        float[NN*D]              25.6 MB
#define NEED_A     (OFF_XW + (size_t)NN * D * 4)   // 39,002,112

// K1: per-edge histogram (both directions)
__global__ __launch_bounds__(256) void gc_hist(
    const int2* __restrict__ edges, int* __restrict__ counts)
{
    int e = blockIdx.x * 256 + threadIdx.x;
    if (e >= NE) return;
    int2 p = edges[e];
    atomicAdd(counts + p.x, 1);
    atomicAdd(counts + p.y, 1);
}

// K2: single-block exclusive scan of counts -> row_start, cursor
__global__ __launch_bounds__(1024) void gc_scan(
    const int* __restrict__ counts, int* __restrict__ row_start,
    int* __restrict__ cursor)
{
    const int CHUNK = (NN + 1023) / 1024;   // 49
    __shared__ int part[1024];
    int t = threadIdx.x;
    int lo = t * CHUNK, hi = min(lo + CHUNK, NN);
    int s = 0;
    for (int i = lo; i < hi; ++i) s += counts[i];
    part[t] = s;
    __syncthreads();
    for (int off = 1; off < 1024; off <<= 1) {
        int v = (t >= off) ? part[t - off] : 0;
        __syncthreads();
        part[t] += v;
        __syncthreads();
    }
    int run = part[t] - s;                  // exclusive prefix
    for (int i = lo; i < hi; ++i) {
        int c = counts[i];
        row_start[i] = run;
        cursor[i]    = run;
        run += c;
    }
    if (t == 1023) row_start[NN] = part[1023];
}

// K3: fill packed CSR (col, w-bits) via per-node cursors — 1x8B write/direction
__global__ __launch_bounds__(256) void gc_fill(
    const int2* __restrict__ edges, const float* __restrict__ wts,
    int* __restrict__ cursor, int2* __restrict__ csr)
{
    int e = blockIdx.x * 256 + threadIdx.x;
    if (e >= NE) return;
    int2 p = edges[e];
    int wb = __float_as_int(wts[e]);
    int pos = atomicAdd(cursor + p.y, 1);
    csr[pos] = make_int2(p.x, wb);
    pos = atomicAdd(cursor + p.x, 1);
    csr[pos] = make_int2(p.y, wb);
}

// K4: gather from feature matrix F, fused degree + normalization -> out.
// One 64-lane wave per node; lane owns a float2 of the row.
__global__ __launch_bounds__(256) void gc_gather(
    const int* __restrict__ row_start, const int2* __restrict__ csr,
    const float* __restrict__ F, float* __restrict__ out)
{
    int wid  = (blockIdx.x * 256 + threadIdx.x) >> 6;
    int lane = threadIdx.x & 63;
    if (wid >= NN) return;
    int j   = row_start[wid];
    int end = row_start[wid + 1];
    const float2* F2 = reinterpret_cast<const float2*>(F);
    float ax = 0.f, ay = 0.f, dw = 0.f;
    for (; j < end; ++j) {
        int2  cw = csr[j];                       // broadcast 8B load
        float w  = __int_as_float(cw.y);
        float2 xv = F2[(size_t)cw.x * 64 + lane];// coalesced 512B row read
        ax = fmaf(w, xv.x, ax);
        ay = fmaf(w, xv.y, ay);
        dw += w;
    }
    float inv = dw > 0.f ? 1.f / dw : 0.f;
    float2 r; r.x = ax * inv; r.y = ay * inv;
    reinterpret_cast<float2*>(out)[(size_t)wid * 64 + lane] = r;
}

// K5: dst_rows = src_rows @ W. Safe for src==dst (block reads only its rows).
__global__ __launch_bounds__(256) void gc_gemm(
    const float* __restrict__ src, float* __restrict__ dst,
    const float* __restrict__ Wm)
{
    __shared__ float Ws[D * D];        // 64 KB
    __shared__ float axs[16 * D];      // 8 KB
    const int tid = threadIdx.x;
    const int col = tid & 127;
    const int ty  = tid >> 7;
    const int rbase = blockIdx.x * 16;

    const float4* W4  = reinterpret_cast<const float4*>(Wm);
    float4*       Ws4 = reinterpret_cast<float4*>(Ws);
    #pragma unroll
    for (int i = 0; i < 16; ++i) Ws4[tid + i * 256] = W4[tid + i * 256];

    const float4* A4   = reinterpret_cast<const float4*>(src + (size_t)rbase * D);
    float4*       axs4 = reinterpret_cast<float4*>(axs);
    #pragma unroll
    for (int i = 0; i < 2; ++i) axs4[tid + i * 256] = A4[tid + i * 256];
    __syncthreads();

    float acc[8];
    #pragma unroll
    for (int i = 0; i < 8; ++i) acc[i] = 0.f;

    for (int k = 0; k < D; ++k) {
        float wv = Ws[k * D + col];
        #pragma unroll
        for (int i = 0; i < 8; ++i)
            acc[i] = fmaf(axs[(ty * 8 + i) * D + k], wv, acc[i]);
    }

    #pragma unroll
    for (int i = 0; i < 8; ++i)
        dst[(size_t)(rbase + ty * 8 + i) * D + col] = acc[i];
}

extern "C" void kernel_launch(void* const* d_in, const int* in_sizes, int n_in,
                              void* d_out, int out_size, void* d_ws, size_t ws_size,
                              hipStream_t stream) {
    const float* X     = (const float*)d_in[0];   // [N,128]
    const int2*  edges = (const int2*)d_in[1];    // [E,2]
    const float* wts   = (const float*)d_in[2];   // [E]
    const float* Wm    = (const float*)d_in[3];   // [128,128]
    float* out = (float*)d_out;                   // [N,128]

    char* ws = (char*)d_ws;
    int*   counts    = (int*) (ws + OFF_CNT);
    int*   row_start = (int*) (ws + OFF_ROW);
    int*   cursor    = (int*) (ws + OFF_CUR);
    int2*  csr       = (int2*)(ws + OFF_CSR);
    float* xw        = (float*)(ws + OFF_XW);

    hipMemsetAsync(counts, 0, NN * sizeof(int), stream);

    const int eblocks = (NE + 255) / 256;
    gc_hist<<<eblocks, 256, 0, stream>>>(edges, counts);
    gc_scan<<<1, 1024, 0, stream>>>(counts, row_start, cursor);
    gc_fill<<<eblocks, 256, 0, stream>>>(edges, wts, cursor, csr);

    if (ws_size >= NEED_A) {
        // Path A: XW = X @ W first, then normalized gather -> out (final)
        gc_gemm<<<NN / 16, 256, 0, stream>>>(X, xw, Wm);
        gc_gather<<<(NN * 64 + 255) / 256, 256, 0, stream>>>(row_start, csr, xw, out);
    } else {
        // Path B: gather X -> out (normalized), then in-place @ W
        gc_gather<<<(NN * 64 + 255) / 256, 256, 0, stream>>>(row_start, csr, X, out);
        gc_gemm<<<NN / 16, 256, 0, stream>>>(out, out, Wm);
    }
}

// Round 4
// 427.584 us; speedup vs baseline: 6.6147x; 1.2243x over previous
//
#include <hip/hip_runtime.h>

#define NN 50000
#define NE 800000
#define D  128

// ---- workspace layout (bytes) ----
#define OFF_CNT    0           // counts    int[NN]
#define OFF_ROW    200704      // row_start int[NN+1]
#define OFF_CUR    401408      // cursor    int[NN]
#define OFF_CSR    602112      // csr       int2[2E]   12.8 MB
#define OFF_XW     13402112    // XW bf16   ushort[NN*D]  12.8 MB
#define NEED_A     (OFF_XW + (size_t)NN * D * 2)   // ~26.2 MB

// K1: per-edge histogram (both directions)
__global__ __launch_bounds__(256) void gc_hist(
    const int2* __restrict__ edges, int* __restrict__ counts)
{
    int e = blockIdx.x * 256 + threadIdx.x;
    if (e >= NE) return;
    int2 p = edges[e];
    atomicAdd(counts + p.x, 1);
    atomicAdd(counts + p.y, 1);
}

// K2: single-block exclusive scan of counts -> row_start, cursor
__global__ __launch_bounds__(1024) void gc_scan(
    const int* __restrict__ counts, int* __restrict__ row_start,
    int* __restrict__ cursor)
{
    const int CHUNK = (NN + 1023) / 1024;   // 49
    __shared__ int part[1024];
    int t = threadIdx.x;
    int lo = t * CHUNK, hi = min(lo + CHUNK, NN);
    int s = 0;
    for (int i = lo; i < hi; ++i) s += counts[i];
    part[t] = s;
    __syncthreads();
    for (int off = 1; off < 1024; off <<= 1) {
        int v = (t >= off) ? part[t - off] : 0;
        __syncthreads();
        part[t] += v;
        __syncthreads();
    }
    int run = part[t] - s;                  // exclusive prefix
    for (int i = lo; i < hi; ++i) {
        int c = counts[i];
        row_start[i] = run;
        cursor[i]    = run;
        run += c;
    }
    if (t == 1023) row_start[NN] = part[1023];
}

// K3: fill packed CSR (col, w-bits) via per-node cursors
__global__ __launch_bounds__(256) void gc_fill(
    const int2* __restrict__ edges, const float* __restrict__ wts,
    int* __restrict__ cursor, int2* __restrict__ csr)
{
    int e = blockIdx.x * 256 + threadIdx.x;
    if (e >= NE) return;
    int2 p = edges[e];
    int wb = __float_as_int(wts[e]);
    int pos = atomicAdd(cursor + p.y, 1);
    csr[pos] = make_int2(p.x, wb);
    pos = atomicAdd(cursor + p.x, 1);
    csr[pos] = make_int2(p.y, wb);
}

// bf16-pair unpack helpers (packed as ushort2 in a uint)
__device__ __forceinline__ float bf_lo(unsigned int v) { return __uint_as_float(v << 16); }
__device__ __forceinline__ float bf_hi(unsigned int v) { return __uint_as_float(v & 0xffff0000u); }

// K4a: gather from bf16 feature matrix F (packed 2 feats/uint), fused
// degree + normalization -> out (final). One 64-lane wave per node; lane
// owns feats [2*lane, 2*lane+1]. 4x unrolled for load-latency ILP.
__global__ __launch_bounds__(256) void gc_gather_bf16(
    const int* __restrict__ row_start, const int2* __restrict__ csr,
    const unsigned int* __restrict__ F, float* __restrict__ out)
{
    int wid  = (blockIdx.x * 256 + threadIdx.x) >> 6;
    int lane = threadIdx.x & 63;
    if (wid >= NN) return;
    int j   = row_start[wid];
    int end = row_start[wid + 1];
    float ax = 0.f, ay = 0.f, dw = 0.f;
    for (; j + 4 <= end; j += 4) {
        int2 c0 = csr[j], c1 = csr[j + 1], c2 = csr[j + 2], c3 = csr[j + 3];
        unsigned int v0 = F[(size_t)c0.x * 64 + lane];
        unsigned int v1 = F[(size_t)c1.x * 64 + lane];
        unsigned int v2 = F[(size_t)c2.x * 64 + lane];
        unsigned int v3 = F[(size_t)c3.x * 64 + lane];
        float w0 = __int_as_float(c0.y), w1 = __int_as_float(c1.y);
        float w2 = __int_as_float(c2.y), w3 = __int_as_float(c3.y);
        ax = fmaf(w0, bf_lo(v0), ax); ay = fmaf(w0, bf_hi(v0), ay);
        ax = fmaf(w1, bf_lo(v1), ax); ay = fmaf(w1, bf_hi(v1), ay);
        ax = fmaf(w2, bf_lo(v2), ax); ay = fmaf(w2, bf_hi(v2), ay);
        ax = fmaf(w3, bf_lo(v3), ax); ay = fmaf(w3, bf_hi(v3), ay);
        dw += w0 + w1 + w2 + w3;
    }
    for (; j < end; ++j) {
        int2 cw = csr[j];
        float w = __int_as_float(cw.y);
        unsigned int v = F[(size_t)cw.x * 64 + lane];
        ax = fmaf(w, bf_lo(v), ax); ay = fmaf(w, bf_hi(v), ay);
        dw += w;
    }
    float inv = dw > 0.f ? 1.f / dw : 0.f;
    float2 r; r.x = ax * inv; r.y = ay * inv;
    reinterpret_cast<float2*>(out)[(size_t)wid * 64 + lane] = r;
}

// K4b (fallback): fp32 gather from F, normalized -> out
__global__ __launch_bounds__(256) void gc_gather_f32(
    const int* __restrict__ row_start, const int2* __restrict__ csr,
    const float* __restrict__ F, float* __restrict__ out)
{
    int wid  = (blockIdx.x * 256 + threadIdx.x) >> 6;
    int lane = threadIdx.x & 63;
    if (wid >= NN) return;
    int j   = row_start[wid];
    int end = row_start[wid + 1];
    const float2* F2 = reinterpret_cast<const float2*>(F);
    float ax = 0.f, ay = 0.f, dw = 0.f;
    for (; j < end; ++j) {
        int2  cw = csr[j];
        float w  = __int_as_float(cw.y);
        float2 xv = F2[(size_t)cw.x * 64 + lane];
        ax = fmaf(w, xv.x, ax);
        ay = fmaf(w, xv.y, ay);
        dw += w;
    }
    float inv = dw > 0.f ? 1.f / dw : 0.f;
    float2 r; r.x = ax * inv; r.y = ay * inv;
    reinterpret_cast<float2*>(out)[(size_t)wid * 64 + lane] = r;
}

// K5a: dst_bf16 = src @ W  (bf16 RNE output, packed)
__global__ __launch_bounds__(256) void gc_gemm_bf16(
    const float* __restrict__ src, unsigned short* __restrict__ dst,
    const float* __restrict__ Wm)
{
    __shared__ float Ws[D * D];        // 64 KB
    __shared__ float axs[16 * D];      // 8 KB
    const int tid = threadIdx.x;
    const int col = tid & 127;
    const int ty  = tid >> 7;
    const int rbase = blockIdx.x * 16;

    const float4* W4  = reinterpret_cast<const float4*>(Wm);
    float4*       Ws4 = reinterpret_cast<float4*>(Ws);
    #pragma unroll
    for (int i = 0; i < 16; ++i) Ws4[tid + i * 256] = W4[tid + i * 256];

    const float4* A4   = reinterpret_cast<const float4*>(src + (size_t)rbase * D);
    float4*       axs4 = reinterpret_cast<float4*>(axs);
    #pragma unroll
    for (int i = 0; i < 2; ++i) axs4[tid + i * 256] = A4[tid + i * 256];
    __syncthreads();

    float acc[8];
    #pragma unroll
    for (int i = 0; i < 8; ++i) acc[i] = 0.f;

    for (int k = 0; k < D; ++k) {
        float wv = Ws[k * D + col];
        #pragma unroll
        for (int i = 0; i < 8; ++i)
            acc[i] = fmaf(axs[(ty * 8 + i) * D + k], wv, acc[i]);
    }

    #pragma unroll
    for (int i = 0; i < 8; ++i) {
        unsigned int b = __float_as_uint(acc[i]);
        unsigned int r = (b + 0x7fffu + ((b >> 16) & 1u)) >> 16;   // RNE
        dst[(size_t)(rbase + ty * 8 + i) * D + col] = (unsigned short)r;
    }
}

// K5b (fallback): dst = src @ W fp32, safe in-place
__global__ __launch_bounds__(256) void gc_gemm_f32(
    const float* __restrict__ src, float* __restrict__ dst,
    const float* __restrict__ Wm)
{
    __shared__ float Ws[D * D];
    __shared__ float axs[16 * D];
    const int tid = threadIdx.x;
    const int col = tid & 127;
    const int ty  = tid >> 7;
    const int rbase = blockIdx.x * 16;

    const float4* W4  = reinterpret_cast<const float4*>(Wm);
    float4*       Ws4 = reinterpret_cast<float4*>(Ws);
    #pragma unroll
    for (int i = 0; i < 16; ++i) Ws4[tid + i * 256] = W4[tid + i * 256];

    const float4* A4   = reinterpret_cast<const float4*>(src + (size_t)rbase * D);
    float4*       axs4 = reinterpret_cast<float4*>(axs);
    #pragma unroll
    for (int i = 0; i < 2; ++i) axs4[tid + i * 256] = A4[tid + i * 256];
    __syncthreads();

    float acc[8];
    #pragma unroll
    for (int i = 0; i < 8; ++i) acc[i] = 0.f;

    for (int k = 0; k < D; ++k) {
        float wv = Ws[k * D + col];
        #pragma unroll
        for (int i = 0; i < 8; ++i)
            acc[i] = fmaf(axs[(ty * 8 + i) * D + k], wv, acc[i]);
    }

    #pragma unroll
    for (int i = 0; i < 8; ++i)
        dst[(size_t)(rbase + ty * 8 + i) * D + col] = acc[i];
}

extern "C" void kernel_launch(void* const* d_in, const int* in_sizes, int n_in,
                              void* d_out, int out_size, void* d_ws, size_t ws_size,
                              hipStream_t stream) {
    const float* X     = (const float*)d_in[0];
    const int2*  edges = (const int2*)d_in[1];
    const float* wts   = (const float*)d_in[2];
    const float* Wm    = (const float*)d_in[3];
    float* out = (float*)d_out;

    char* ws = (char*)d_ws;
    int*   counts    = (int*) (ws + OFF_CNT);
    int*   row_start = (int*) (ws + OFF_ROW);
    int*   cursor    = (int*) (ws + OFF_CUR);
    int2*  csr       = (int2*)(ws + OFF_CSR);

    hipMemsetAsync(counts, 0, NN * sizeof(int), stream);

    const int eblocks = (NE + 255) / 256;
    gc_hist<<<eblocks, 256, 0, stream>>>(edges, counts);
    gc_scan<<<1, 1024, 0, stream>>>(counts, row_start, cursor);
    gc_fill<<<eblocks, 256, 0, stream>>>(edges, wts, cursor, csr);

    if (ws_size >= NEED_A) {
        unsigned short* xw = (unsigned short*)(ws + OFF_XW);
        gc_gemm_bf16<<<NN / 16, 256, 0, stream>>>(X, xw, Wm);
        gc_gather_bf16<<<(NN * 64 + 255) / 256, 256, 0, stream>>>(
            row_start, csr, (const unsigned int*)xw, out);
    } else {
        gc_gather_f32<<<(NN * 64 + 255) / 256, 256, 0, stream>>>(row_start, csr, X, out);
        gc_gemm_f32<<<NN / 16, 256, 0, stream>>>(out, out, Wm);
    }
}